// Round 8
// baseline (282.116 us; speedup 1.0000x reference)
//
#include <hip/hip_runtime.h>
#include <hip/hip_bf16.h>

#define Bq 2
#define Hh 16
#define Ss 2048
#define Dm 1024
#define Dk 64
// softmax scale 1/sqrt(64)=0.125 is pre-folded (with log2e) into Q at the
// gemm_qkv epilogue: QSC = 0.125 * log2(e). flash/attn_mean then use exp2.
#define QSC 0.18033688f

typedef _Float16 f16x8 __attribute__((ext_vector_type(8)));
typedef _Float16 f16x4 __attribute__((ext_vector_type(4)));
typedef _Float16 f16x2 __attribute__((ext_vector_type(2)));
typedef float    f32x4 __attribute__((ext_vector_type(4)));
typedef float    f32x16 __attribute__((ext_vector_type(16)));
typedef unsigned int u32x4 __attribute__((ext_vector_type(4)));

// MFMA fragment layouts:
// 16x16x32 f16: A[m=lane&15][k=(lane>>4)*8+j]; B[k=(lane>>4)*8+j][n=lane&15];
//               C/D col=lane&15, row=(lane>>4)*4+reg.
// 32x32x16 f16: A[m=lane&31][k=(lane>>5)*8+j]; B[k=(lane>>5)*8+j][n=lane&31];
//               C/D col=lane&31, row=(reg&3)+8*(reg>>2)+4*(lane>>5).
//
// LDS tiles are stored as [row][128B] with XOR swizzle byte ^= ((row&7)<<4):
// write-side and read-side use the same involution -> bank-group-even access.

__device__ __forceinline__ void gl_lds16(const void* g, void* lds) {
    __builtin_amdgcn_global_load_lds(
        (const __attribute__((address_space(1))) void*)g,
        (__attribute__((address_space(3))) void*)lds, 16, 0, 0);
}

extern "C" __device__ float __ocml_exp2_f32(float);

__device__ __forceinline__ float exp2_fast(float x) {
#if __has_builtin(__builtin_amdgcn_exp2f)
    return __builtin_amdgcn_exp2f(x);     // v_exp_f32: D = 2^S0
#else
    return __ocml_exp2_f32(x);
#endif
}

__device__ __forceinline__ float rcp_fast(float x) {
#if __has_builtin(__builtin_amdgcn_rcpf)
    return __builtin_amdgcn_rcpf(x);      // v_rcp_f32, ~1 ulp
#else
    float r; asm("v_rcp_f32 %0, %1" : "=v"(r) : "v"(x)); return r;
#endif
}

__device__ __forceinline__ unsigned int pk_u32(float a, float b) {
    return __builtin_bit_cast(unsigned int, __builtin_amdgcn_cvt_pkrtz(a, b));
}

// v_permlane32_swap_b32: a.lanes[32:63] <-> b.lanes[0:31].
// After: a = {a.lo | b.lo}, b = {a.hi | b.hi}.
__device__ __forceinline__ void plane32_swap(unsigned int& a, unsigned int& b) {
    asm volatile("v_permlane32_swap_b32 %0, %1" : "+v"(a), "+v"(b));
}

// ---------------------------------------------------------------------------
// Convert all f32 inputs to f16 once.
__global__ __launch_bounds__(256) void convert_kernel(
    const float* __restrict__ q, const float* __restrict__ k,
    const float* __restrict__ v, const float* __restrict__ wq,
    const float* __restrict__ wk, const float* __restrict__ wv,
    const float* __restrict__ wo,
    _Float16* __restrict__ qd, _Float16* __restrict__ kd,
    _Float16* __restrict__ vd, _Float16* __restrict__ wd)
{
    int seg = blockIdx.y;
    const float* src; _Float16* dst; int n4;
    switch (seg) {
        case 0: src = q; dst = qd; n4 = 1048576; break;
        case 1: src = k; dst = kd; n4 = 1048576; break;
        case 2: src = v; dst = vd; n4 = 1048576; break;
        default:
            src = (seg == 3) ? wq : (seg == 4) ? wk : (seg == 5) ? wv : wo;
            dst = wd + (size_t)(seg - 3) * 1048576;
            n4 = 262144;
    }
    for (int i = blockIdx.x * 256 + threadIdx.x; i < n4; i += gridDim.x * 256) {
        float4 x = ((const float4*)src)[i];
        f16x4 h = {(_Float16)x.x, (_Float16)x.y, (_Float16)x.z, (_Float16)x.w};
        ((f16x4*)dst)[i] = h;
    }
}

// ---------------------------------------------------------------------------
// Fused Q/K/V projection GEMM (f16 in, global_load_lds staging, 128x128 tile).
// z==0 (Q) output is pre-scaled by QSC so attention kernels can use raw exp2.
// z==2 (V) epilogue: LDS-transpose then COALESCED 16B stores of V^T rows.
__global__ __launch_bounds__(256) void gemm_qkv(
    const _Float16* __restrict__ qf, const _Float16* __restrict__ kf,
    const _Float16* __restrict__ vf, const _Float16* __restrict__ Wh,
    _Float16* __restrict__ Qd, _Float16* __restrict__ Kd,
    _Float16* __restrict__ Vd)
{
    __shared__ alignas(16) char smem[32768];
    _Float16* As = (_Float16*)smem;            // 128*32 f16 (8 KB)
    _Float16* Ws = (_Float16*)(smem + 8192);   // 128*32 f16 (8 KB)
    int z = blockIdx.z;
    const _Float16* A = (z == 0) ? qf : (z == 1) ? kf : vf;
    const _Float16* W = Wh + (size_t)z * (Dm * Dm);
    int t = threadIdx.x, lane = t & 63, w = t >> 6;
    int quad = lane >> 4, l15 = lane & 15;
    int wm = w & 1, wn = w >> 1;
    int n0 = blockIdx.x * 128, m0 = blockIdx.y * 128;

    f32x4 acc[4][4] = {};
    for (int k0 = 0; k0 < Dm; k0 += 32) {
        __syncthreads();
        for (int j = 0; j < 2; ++j) {
            int ca = w * 128 + j * 64 + lane;
            int row = ca >> 2, c8 = (ca & 3) * 8;
            gl_lds16(&A[(size_t)(m0 + row) * Dm + k0 + c8],
                     &As[(size_t)(w * 128 + j * 64) * 8]);
            gl_lds16(&W[(size_t)(n0 + row) * Dm + k0 + c8],
                     &Ws[(size_t)(w * 128 + j * 64) * 8]);
        }
        __syncthreads();
        f16x8 af[4], bf[4];
        for (int mi = 0; mi < 4; ++mi)
            af[mi] = *(const f16x8*)&As[(wm * 64 + mi * 16 + l15) * 32 + quad * 8];
        for (int ni = 0; ni < 4; ++ni)
            bf[ni] = *(const f16x8*)&Ws[(wn * 64 + ni * 16 + l15) * 32 + quad * 8];
        for (int mi = 0; mi < 4; ++mi)
            for (int ni = 0; ni < 4; ++ni)
                acc[mi][ni] = __builtin_amdgcn_mfma_f32_16x16x32_f16(
                    af[mi], bf[ni], acc[mi][ni], 0, 0, 0);
    }

    if (z == 2) {
        // V^T epilogue: C^T tile into LDS (swizzled), coalesced stores.
        __syncthreads();                       // all As/Ws reads complete
        for (int mi = 0; mi < 4; ++mi)
            for (int ni = 0; ni < 4; ++ni) {
                int n_l = wn * 64 + ni * 16 + l15;
                int m_b = wm * 64 + mi * 16 + quad * 4;
                f16x4 hv = {(_Float16)acc[mi][ni][0], (_Float16)acc[mi][ni][1],
                            (_Float16)acc[mi][ni][2], (_Float16)acc[mi][ni][3]};
                *(f16x4*)(smem + n_l * 256 + ((m_b * 2) ^ ((n_l & 7) << 4))) = hv;
            }
        __syncthreads();
        int b = m0 >> 11, sb = m0 & (Ss - 1);
        for (int p = 0; p < 8; ++p) {
            int cid = p * 256 + t;             // 2048 chunks: 128 rows x 16
            int rown = cid >> 4, c16 = cid & 15;
            f16x8 v = *(const f16x8*)(smem + rown * 256 +
                                      ((c16 * 16) ^ ((rown & 7) << 4)));
            int n = n0 + rown;
            int h = n >> 6, d = n & 63;
            *(f16x8*)&Vd[(((size_t)(b * Hh + h) * Dk + d) << 11) + sb + c16 * 8] = v;
        }
    } else {
        _Float16* Y = (z == 0) ? Qd : Kd;
        float osc = (z == 0) ? QSC : 1.0f;
        for (int mi = 0; mi < 4; ++mi)
            for (int ni = 0; ni < 4; ++ni)
                for (int r = 0; r < 4; ++r) {
                    int m = m0 + wm * 64 + mi * 16 + quad * 4 + r;
                    int n = n0 + wn * 64 + ni * 16 + l15;
                    int b = m >> 11, s = m & (Ss - 1);
                    int h = n >> 6,  d = n & 63;
                    Y[(((size_t)(b * Hh + h) * Ss + s) << 6) + d] =
                        (_Float16)(acc[mi][ni][r] * osc);
                }
    }
}

// ---------------------------------------------------------------------------
// Out-projection: out = HO(f16) @ Wo^T -> f32. 128x64 tile.
__global__ __launch_bounds__(256) void gemm_out(
    const _Float16* __restrict__ HO, const _Float16* __restrict__ Woh,
    float* __restrict__ out)
{
    __shared__ _Float16 As[128 * 32];
    __shared__ _Float16 Ws[64 * 32];
    int t = threadIdx.x, lane = t & 63, w = t >> 6;
    int quad = lane >> 4, l15 = lane & 15;
    int n0 = blockIdx.x * 64, m0 = blockIdx.y * 128;

    f32x4 acc[2][4] = {};
    for (int k0 = 0; k0 < Dm; k0 += 32) {
        __syncthreads();
        for (int j = 0; j < 2; ++j) {
            int ca = w * 128 + j * 64 + lane;
            int row = ca >> 2, c8 = (ca & 3) * 8;
            gl_lds16(&HO[(size_t)(m0 + row) * Dm + k0 + c8],
                     &As[(size_t)(w * 128 + j * 64) * 8]);
        }
        {
            int cw = w * 64 + lane;
            int row = cw >> 2, c8 = (cw & 3) * 8;
            gl_lds16(&Woh[(size_t)(n0 + row) * Dm + k0 + c8],
                     &Ws[(size_t)(w * 64) * 8]);
        }
        __syncthreads();
        f16x8 af[2], bf[4];
        for (int mi = 0; mi < 2; ++mi)
            af[mi] = *(const f16x8*)&As[(w * 32 + mi * 16 + l15) * 32 + quad * 8];
        for (int ni = 0; ni < 4; ++ni)
            bf[ni] = *(const f16x8*)&Ws[(ni * 16 + l15) * 32 + quad * 8];
        for (int mi = 0; mi < 2; ++mi)
            for (int ni = 0; ni < 4; ++ni)
                acc[mi][ni] = __builtin_amdgcn_mfma_f32_16x16x32_f16(
                    af[mi], bf[ni], acc[mi][ni], 0, 0, 0);
    }
    for (int mi = 0; mi < 2; ++mi)
        for (int ni = 0; ni < 4; ++ni)
            for (int r = 0; r < 4; ++r) {
                int m = m0 + w * 32 + mi * 16 + quad * 4 + r;
                int n = n0 + ni * 16 + l15;
                out[(size_t)m * Dm + n] = acc[mi][ni][r];
            }
}

// ---------------------------------------------------------------------------
// Flash attention v10 (m == 0): k-split x2, 128-q tile, 32 q/wave.
// 32x32x16 MFMAs throughout. S^T = K Q^T leaves P in a layout where the PV
// B-operand (O^T = V^T P^T) is reachable with 4 cvt_pk + 2 permlane32_swap
// per 16-k block -- NO Ps LDS round-trip. K/V staging identical to v7
// (reg-prefetch, XOR swizzle, 2 barriers/tile). l-sum on VALU + end shfl.
// Freed LDS hosts a per-wave O^T->O transpose for coalesced partial stores.
__global__ __launch_bounds__(256) void flash_kernel(
    const _Float16* __restrict__ Qh, const _Float16* __restrict__ Kh,
    const _Float16* __restrict__ Vt, _Float16* __restrict__ Op,
    float* __restrict__ lp)
{
    __shared__ alignas(16) char Ks[8192];      // 64 k-rows x 128B, swizzled
    __shared__ alignas(16) char Vs[8192];      // 64 d-rows x 128B (k), swizzled
    __shared__ alignas(16) char Ot[4][4096];   // per-wave O^T transpose buffer
    int t = threadIdx.x;
    int lane = t & 63, w = t >> 6;
    int hi = lane >> 5, l31 = lane & 31;
    int bh = blockIdx.x;
    int q0 = blockIdx.y * 128 + w * 32;
    int ks = blockIdx.z;
    int kt0 = ks * 16, kt1 = kt0 + 16;

    const _Float16* Qp = Qh + (size_t)bh * Ss * Dk;
    const _Float16* Kp = Kh + (size_t)bh * Ss * Dk;
    const _Float16* Vp = Vt + (size_t)bh * Dk * Ss;

    // Q^T B-fragments (constant over k-loop): B[d=dblk*16+hi*8+j][q=l31]
    f16x8 qB[4];
#pragma unroll
    for (int dblk = 0; dblk < 4; ++dblk)
        qB[dblk] = *(const f16x8*)&Qp[(size_t)(q0 + l31) * Dk + dblk * 16 + hi * 8];

    // staging coords: thread t covers rows (t>>3), (t>>3)+32; 16B col (t&7)*16
    int srow0 = t >> 3;
    int colh  = (t & 7) * 8;                   // halves
    int sw0 = srow0 * 128 + ((colh * 2) ^ ((srow0 & 7) << 4));
    int sw1 = sw0 + 32 * 128;                  // (srow0+32)&7 == srow0&7
    int swzr = (l31 & 7) << 4;                 // read-side XOR (row&7 == l31&7)

    // prefetch first k-tile into registers
    f16x8 kr0 = *(const f16x8*)&Kp[(size_t)(kt0 * 64 + srow0) * Dk + colh];
    f16x8 kr1 = *(const f16x8*)&Kp[(size_t)(kt0 * 64 + srow0 + 32) * Dk + colh];
    f16x8 vr0 = *(const f16x8*)&Vp[(size_t)srow0 * Ss + kt0 * 64 + colh];
    f16x8 vr1 = *(const f16x8*)&Vp[(size_t)(srow0 + 32) * Ss + kt0 * 64 + colh];

    f32x16 oacc[2] = {};                       // O^T[d=d2*32+row(reg,hi)][q=l31]
    float lsum = 0.f;

    for (int kt = kt0; kt < kt1; ++kt) {
        __syncthreads();                 // prev iter's LDS reads complete
        *(f16x8*)(Ks + sw0) = kr0;
        *(f16x8*)(Ks + sw1) = kr1;
        *(f16x8*)(Vs + sw0) = vr0;
        *(f16x8*)(Vs + sw1) = vr1;
        if (kt + 1 < kt1) {              // prefetch next tile (overlaps compute)
            kr0 = *(const f16x8*)&Kp[(size_t)((kt + 1) * 64 + srow0) * Dk + colh];
            kr1 = *(const f16x8*)&Kp[(size_t)((kt + 1) * 64 + srow0 + 32) * Dk + colh];
            vr0 = *(const f16x8*)&Vp[(size_t)srow0 * Ss + (kt + 1) * 64 + colh];
            vr1 = *(const f16x8*)&Vp[(size_t)(srow0 + 32) * Ss + (kt + 1) * 64 + colh];
        }
        __syncthreads();                 // tile visible

        // Phase A: S^T = K Q^T (2 x 32x32 k-blocks), exp2, pack, lane-swap.
        // C row = (reg&3)+8*(reg>>2)+4*hi (k within 32-block), col = q = l31.
        unsigned int bf[4][4];           // P^T B-frag dwords per 16-k block
#pragma unroll
        for (int kb = 0; kb < 2; ++kb) {
            f32x16 C = {};
            const char* rb = Ks + ((kb * 32 + l31) << 7);
#pragma unroll
            for (int dblk = 0; dblk < 4; ++dblk) {
                f16x8 kf = *(const f16x8*)(rb + ((dblk * 32 + hi * 16) ^ swzr));
                C = __builtin_amdgcn_mfma_f32_32x32x16_f16(kf, qB[dblk], C, 0, 0, 0);
            }
#pragma unroll
            for (int h = 0; h < 2; ++h) {
                float p0 = exp2_fast(C[h * 8 + 0]), p1 = exp2_fast(C[h * 8 + 1]);
                float p2 = exp2_fast(C[h * 8 + 2]), p3 = exp2_fast(C[h * 8 + 3]);
                float p4 = exp2_fast(C[h * 8 + 4]), p5 = exp2_fast(C[h * 8 + 5]);
                float p6 = exp2_fast(C[h * 8 + 6]), p7 = exp2_fast(C[h * 8 + 7]);
                lsum += ((p0 + p1) + (p2 + p3)) + ((p4 + p5) + (p6 + p7));
                unsigned int d01 = pk_u32(p0, p1), d23 = pk_u32(p2, p3);
                unsigned int d45 = pk_u32(p4, p5), d67 = pk_u32(p6, p7);
                plane32_swap(d01, d45);  // d01 = t0, d45 = t2 (both halves)
                plane32_swap(d23, d67);  // d23 = t1, d67 = t3
                int kblk = kb * 2 + h;
                bf[kblk][0] = d01; bf[kblk][1] = d23;
                bf[kblk][2] = d45; bf[kblk][3] = d67;
            }
        }

        // Phase B: O^T += V^T P^T. A = V^T rows (direct from Vs), B = bf.
#pragma unroll
        for (int kblk = 0; kblk < 4; ++kblk) {
            u32x4 pb = {bf[kblk][0], bf[kblk][1], bf[kblk][2], bf[kblk][3]};
            f16x8 pB = __builtin_bit_cast(f16x8, pb);
#pragma unroll
            for (int d2 = 0; d2 < 2; ++d2) {
                const char* rb = Vs + ((d2 * 32 + l31) << 7);
                f16x8 vA = *(const f16x8*)(rb + ((kblk * 32 + hi * 16) ^ swzr));
                oacc[d2] = __builtin_amdgcn_mfma_f32_32x32x16_f16(
                    vA, pB, oacc[d2], 0, 0, 0);
            }
        }
    }

    // l[q]: lane holds partial over its k-rows; other half has the rest.
    lsum += __shfl_xor(lsum, 32);

    // O^T -> O via per-wave LDS transpose, then coalesced 16B stores.
    char* Ow = Ot[w];
#pragma unroll
    for (int d2 = 0; d2 < 2; ++d2)
#pragma unroll
        for (int g = 0; g < 4; ++g) {
            f16x4 hv = {(_Float16)oacc[d2][g * 4 + 0], (_Float16)oacc[d2][g * 4 + 1],
                        (_Float16)oacc[d2][g * 4 + 2], (_Float16)oacc[d2][g * 4 + 3]};
            int d = d2 * 32 + g * 8 + hi * 4;
            *(f16x4*)(Ow + l31 * 128 + ((d * 2) ^ swzr)) = hv;
        }
    __syncthreads();
    _Float16* Od = Op + (size_t)ks * (Bq * Hh * Ss * Dk) + (size_t)bh * Ss * Dk;
#pragma unroll
    for (int i = 0; i < 4; ++i) {
        f16x8 v = *(const f16x8*)(Ow + l31 * 128 + ((hi * 64 + i * 16) ^ swzr));
        *(f16x8*)&Od[(size_t)(q0 + l31) * Dk + hi * 32 + i * 8] = v;
    }
    if (lane < 32)
        lp[(size_t)ks * 65536 + (size_t)bh * Ss + q0 + l31] = lsum;
}

// ---------------------------------------------------------------------------
// Fold the 2 k-split partials: HO = (O0+O1)/l, lw = l0+l1.
__global__ __launch_bounds__(256) void reduce_kernel(
    const _Float16* __restrict__ Op, const float* __restrict__ lp,
    _Float16* __restrict__ HO, float* __restrict__ lw)
{
    int i = blockIdx.x * 256 + threadIdx.x;    // f16x4 index, 0..1048575
    int d4  = i & 15;                          // 4-elem group within d (64)
    int row = i >> 4;                          // bh*Ss + q
    f16x4 a = ((const f16x4*)Op)[i];
    f16x4 b = ((const f16x4*)Op)[i + 1048576];
    float l = lp[row] + lp[65536 + row];
    float inv = rcp_fast(l);
    int bh = row >> 11, q = row & (Ss - 1);
    int b_ = bh >> 4,  h = bh & 15;
    f16x4 o;
    for (int j = 0; j < 4; ++j)
        o[j] = (_Float16)(((float)a[j] + (float)b[j]) * inv);
    *(f16x4*)&HO[((size_t)(b_ * Ss + q)) * Dm + h * Dk + d4 * 4] = o;
    if (d4 == 0) lw[row] = l;
}

// ---------------------------------------------------------------------------
// attn_weights = mean over heads of exp2(s)/l. R5 version: reg-staged K,
// 2 barriers/head, Q/l reg-prefetch, XOR-swizzled Ks layout.
__global__ __launch_bounds__(256) void attn_mean_kernel(
    const _Float16* __restrict__ Qh, const _Float16* __restrict__ Kh,
    const float* __restrict__ lw, float* __restrict__ out_attn)
{
    __shared__ alignas(16) char Ks[8192];      // 64 rows x 128B, swizzled
    int t = threadIdx.x;
    int lane = t & 63, w = t >> 6;
    int quad = lane >> 4, l15 = lane & 15;
    int k0 = blockIdx.x * 64;
    int q0 = blockIdx.y * 128;
    int b  = blockIdx.z;
    int qrow = q0 + w * 32;

    int srow0 = t >> 3;
    int colh  = (t & 7) * 8;
    int sw0 = srow0 * 128 + ((colh * 2) ^ ((srow0 & 7) << 4));
    int sw1 = sw0 + 32 * 128;
    int swz = (l15 & 7) << 4;

    f16x8 kr0, kr1, qn[2][2];
    float4 ln[2];
    {
        size_t base = (size_t)(b * Hh) * Ss;
        kr0 = *(const f16x8*)&Kh[(base + k0 + srow0) * Dk + colh];
        kr1 = *(const f16x8*)&Kh[(base + k0 + srow0 + 32) * Dk + colh];
#pragma unroll
        for (int qh = 0; qh < 2; ++qh) {
            qn[qh][0] = *(const f16x8*)&Qh[(base + qrow + qh * 16 + l15) * Dk + quad * 8];
            qn[qh][1] = *(const f16x8*)&Qh[(base + qrow + qh * 16 + l15) * Dk + 32 + quad * 8];
            ln[qh] = *(const float4*)&lw[base + qrow + qh * 16 + quad * 4];
        }
    }

    f32x4 acc[2][4] = {};
    for (int h = 0; h < Hh; ++h) {
        __syncthreads();
        *(f16x8*)(Ks + sw0) = kr0;
        *(f16x8*)(Ks + sw1) = kr1;
        f16x8 qf[2][2];
        float4 lv[2];
#pragma unroll
        for (int qh = 0; qh < 2; ++qh) {
            qf[qh][0] = qn[qh][0]; qf[qh][1] = qn[qh][1]; lv[qh] = ln[qh];
        }
        if (h < Hh - 1) {
            size_t base = (size_t)(b * Hh + h + 1) * Ss;
            kr0 = *(const f16x8*)&Kh[(base + k0 + srow0) * Dk + colh];
            kr1 = *(const f16x8*)&Kh[(base + k0 + srow0 + 32) * Dk + colh];
#pragma unroll
            for (int qh = 0; qh < 2; ++qh) {
                qn[qh][0] = *(const f16x8*)&Qh[(base + qrow + qh * 16 + l15) * Dk + quad * 8];
                qn[qh][1] = *(const f16x8*)&Qh[(base + qrow + qh * 16 + l15) * Dk + 32 + quad * 8];
                ln[qh] = *(const float4*)&lw[base + qrow + qh * 16 + quad * 4];
            }
        }
        __syncthreads();

        float ir[2][4];
#pragma unroll
        for (int qh = 0; qh < 2; ++qh) {
            ir[qh][0] = rcp_fast(lv[qh].x); ir[qh][1] = rcp_fast(lv[qh].y);
            ir[qh][2] = rcp_fast(lv[qh].z); ir[qh][3] = rcp_fast(lv[qh].w);
        }
#pragma unroll
        for (int nt = 0; nt < 4; ++nt) {
            const char* rb = Ks + ((nt * 16 + l15) << 7);
            f16x8 b0 = *(const f16x8*)(rb + ((quad * 16) ^ swz));
            f16x8 b1 = *(const f16x8*)(rb + ((64 + quad * 16) ^ swz));
#pragma unroll
            for (int qh = 0; qh < 2; ++qh) {
                f32x4 z = {};
                z = __builtin_amdgcn_mfma_f32_16x16x32_f16(qf[qh][0], b0, z, 0, 0, 0);
                z = __builtin_amdgcn_mfma_f32_16x16x32_f16(qf[qh][1], b1, z, 0, 0, 0);
#pragma unroll
                for (int r = 0; r < 4; ++r)
                    acc[qh][nt][r] += exp2_fast(z[r]) * ir[qh][r];
            }
        }
    }

#pragma unroll
    for (int qh = 0; qh < 2; ++qh)
#pragma unroll
        for (int nt = 0; nt < 4; ++nt)
#pragma unroll
            for (int r = 0; r < 4; ++r) {
                int q = qrow + qh * 16 + quad * 4 + r;
                out_attn[((size_t)(b * Ss + q)) * Ss + k0 + nt * 16 + l15] =
                    acc[qh][nt][r] * (1.0f / Hh);
            }
}

// ---------------------------------------------------------------------------
extern "C" void kernel_launch(void* const* d_in, const int* in_sizes, int n_in,
                              void* d_out, int out_size, void* d_ws, size_t ws_size,
                              hipStream_t stream) {
    const float* query = (const float*)d_in[0];
    const float* key   = (const float*)d_in[1];
    const float* value = (const float*)d_in[2];
    const float* Wq    = (const float*)d_in[3];
    const float* Wk    = (const float*)d_in[4];
    const float* Wv    = (const float*)d_in[5];
    const float* Wo    = (const float*)d_in[6];

    float* out      = (float*)d_out;                  // (B,S,Dm) f32
    float* attn_out = out + (size_t)4194304;          // (B,S,S)  f32, 33.55 MB

    // attn region staging timeline (R5 plan):
    //   [0,     8.39M): HO f16          (reduce writes, gemm_out reads)
    //   [8.39M, 33.55M): qf|kf|vf f16   (convert->gemm_qkv), then REUSED as
    //                    Op0|Op1 f16 partials + lp f32 (flash->reduce)
    _Float16* HO  = (_Float16*)attn_out;
    _Float16* qf  = (_Float16*)(attn_out + 2097152);
    _Float16* kf  = qf + 4194304;
    _Float16* vf  = kf + 4194304;
    _Float16* Op  = qf;                               // 2 x 4194304 halves
    float*    lp  = (float*)(Op + 2 * 4194304);       // 2 x 65536 floats

    _Float16* Qh = (_Float16*)d_ws;
    _Float16* Kh = Qh + (size_t)4194304;
    _Float16* Vt = Kh + (size_t)4194304;
    _Float16* Wh = Vt + (size_t)4194304;              // Wq|Wk|Wv|Wo f16
    float*    lw = (float*)(Wh + (size_t)4194304);

    convert_kernel<<<dim3(256, 7), 256, 0, stream>>>(
        query, key, value, Wq, Wk, Wv, Wo, qf, kf, vf, Wh);

    gemm_qkv<<<dim3(8, 32, 3), 256, 0, stream>>>(qf, kf, vf, Wh, Qh, Kh, Vt);

    flash_kernel<<<dim3(Bq * Hh, Ss / 128, 2), 256, 0, stream>>>(Qh, Kh, Vt, Op, lp);

    reduce_kernel<<<4096, 256, 0, stream>>>(Op, lp, HO, lw);

    gemm_out<<<dim3(16, 32), 256, 0, stream>>>(HO, Wh + (size_t)3 * 1048576, out);

    attn_mean_kernel<<<dim3(Ss / 64, Ss / 128, Bq), 256, 0, stream>>>(
        Qh, Kh, lw, attn_out);
}

// Round 9
// 267.093 us; speedup vs baseline: 1.0562x; 1.0562x over previous
//
#include <hip/hip_runtime.h>
#include <hip/hip_bf16.h>

#define Bq 2
#define Hh 16
#define Ss 2048
#define Dm 1024
#define Dk 64
// softmax scale 1/sqrt(64)=0.125 is pre-folded (with log2e) into Q at the
// gemm_qkv epilogue: QSC = 0.125 * log2(e). flash/attn_mean then use exp2.
#define QSC 0.18033688f

typedef _Float16 f16x8 __attribute__((ext_vector_type(8)));
typedef _Float16 f16x4 __attribute__((ext_vector_type(4)));
typedef _Float16 f16x2 __attribute__((ext_vector_type(2)));
typedef float    f32x4 __attribute__((ext_vector_type(4)));

// MFMA fragment layout (16x16x32 f16):
//   A: lane holds A[m = lane&15][k = (lane>>4)*8 + j], j=0..7  (16B contiguous)
//   B: lane holds B[k = (lane>>4)*8 + j][n = lane&15]   (same register shape)
//   C/D: col = lane&15, row = (lane>>4)*4 + reg
//
// LDS tiles are stored as [row][128B] with XOR swizzle byte ^= ((row&7)<<4):
// write-side and read-side use the same involution -> bank-group-even access.
//
// GEMM grids use an in-kernel XCD-chunked block-id bijection (T1): hardware
// block orig (XCD = orig%8, round-robin) runs logical tile
// (orig%8)*chunk + orig/8, so blocks sharing an A-panel co-locate on one XCD
// and the panel stays L2-resident.

__device__ __forceinline__ void gl_lds16(const void* g, void* lds) {
    __builtin_amdgcn_global_load_lds(
        (const __attribute__((address_space(1))) void*)g,
        (__attribute__((address_space(3))) void*)lds, 16, 0, 0);
}

extern "C" __device__ float __ocml_exp2_f32(float);

__device__ __forceinline__ float exp2_fast(float x) {
#if __has_builtin(__builtin_amdgcn_exp2f)
    return __builtin_amdgcn_exp2f(x);     // v_exp_f32: D = 2^S0
#else
    return __ocml_exp2_f32(x);
#endif
}

__device__ __forceinline__ float rcp_fast(float x) {
#if __has_builtin(__builtin_amdgcn_rcpf)
    return __builtin_amdgcn_rcpf(x);      // v_rcp_f32, ~1 ulp
#else
    float r; asm("v_rcp_f32 %0, %1" : "=v"(r) : "v"(x)); return r;
#endif
}

__device__ __forceinline__ f16x2 pk_f16(float a, float b) {
    return __builtin_bit_cast(f16x2, __builtin_amdgcn_cvt_pkrtz(a, b));
}

// ---------------------------------------------------------------------------
// Convert all f32 inputs to f16 once.
__global__ __launch_bounds__(256) void convert_kernel(
    const float* __restrict__ q, const float* __restrict__ k,
    const float* __restrict__ v, const float* __restrict__ wq,
    const float* __restrict__ wk, const float* __restrict__ wv,
    const float* __restrict__ wo,
    _Float16* __restrict__ qd, _Float16* __restrict__ kd,
    _Float16* __restrict__ vd, _Float16* __restrict__ wd)
{
    int seg = blockIdx.y;
    const float* src; _Float16* dst; int n4;
    switch (seg) {
        case 0: src = q; dst = qd; n4 = 1048576; break;
        case 1: src = k; dst = kd; n4 = 1048576; break;
        case 2: src = v; dst = vd; n4 = 1048576; break;
        default:
            src = (seg == 3) ? wq : (seg == 4) ? wk : (seg == 5) ? wv : wo;
            dst = wd + (size_t)(seg - 3) * 1048576;
            n4 = 262144;
    }
    for (int i = blockIdx.x * 256 + threadIdx.x; i < n4; i += gridDim.x * 256) {
        float4 x = ((const float4*)src)[i];
        f16x4 h = {(_Float16)x.x, (_Float16)x.y, (_Float16)x.z, (_Float16)x.w};
        ((f16x4*)dst)[i] = h;
    }
}

// ---------------------------------------------------------------------------
// Fused Q/K/V projection GEMM (f16 in, global_load_lds staging, 128x128 tile).
// z==0 (Q) output is pre-scaled by QSC so attention kernels can use raw exp2.
// z==2 (V) epilogue: LDS-transpose then COALESCED 16B stores of V^T rows.
// XCD-chunked tile mapping for A/W panel L2 residency.
__global__ __launch_bounds__(256) void gemm_qkv(
    const _Float16* __restrict__ qf, const _Float16* __restrict__ kf,
    const _Float16* __restrict__ vf, const _Float16* __restrict__ Wh,
    _Float16* __restrict__ Qd, _Float16* __restrict__ Kd,
    _Float16* __restrict__ Vd)
{
    __shared__ alignas(16) char smem[32768];
    _Float16* As = (_Float16*)smem;            // 128*32 f16 (8 KB)
    _Float16* Ws = (_Float16*)(smem + 8192);   // 128*32 f16 (8 KB)
    int z = blockIdx.z;
    const _Float16* A = (z == 0) ? qf : (z == 1) ? kf : vf;
    const _Float16* W = Wh + (size_t)z * (Dm * Dm);
    int t = threadIdx.x, lane = t & 63, w = t >> 6;
    int quad = lane >> 4, l15 = lane & 15;
    int wm = w & 1, wn = w >> 1;
    // XCD-chunked bijection: 256 tiles/z, chunk 32/XCD, bx fastest in chunk.
    int orig = blockIdx.y * 8 + blockIdx.x;
    int wgid = (orig & 7) * 32 + (orig >> 3);
    int n0 = (wgid & 7) * 128, m0 = (wgid >> 3) * 128;

    f32x4 acc[4][4] = {};
    for (int k0 = 0; k0 < Dm; k0 += 32) {
        __syncthreads();
        for (int j = 0; j < 2; ++j) {
            int ca = w * 128 + j * 64 + lane;
            int row = ca >> 2, c8 = (ca & 3) * 8;
            gl_lds16(&A[(size_t)(m0 + row) * Dm + k0 + c8],
                     &As[(size_t)(w * 128 + j * 64) * 8]);
            gl_lds16(&W[(size_t)(n0 + row) * Dm + k0 + c8],
                     &Ws[(size_t)(w * 128 + j * 64) * 8]);
        }
        __syncthreads();
        f16x8 af[4], bf[4];
        for (int mi = 0; mi < 4; ++mi)
            af[mi] = *(const f16x8*)&As[(wm * 64 + mi * 16 + l15) * 32 + quad * 8];
        for (int ni = 0; ni < 4; ++ni)
            bf[ni] = *(const f16x8*)&Ws[(wn * 64 + ni * 16 + l15) * 32 + quad * 8];
        for (int mi = 0; mi < 4; ++mi)
            for (int ni = 0; ni < 4; ++ni)
                acc[mi][ni] = __builtin_amdgcn_mfma_f32_16x16x32_f16(
                    af[mi], bf[ni], acc[mi][ni], 0, 0, 0);
    }

    if (z == 2) {
        // V^T epilogue: C^T tile into LDS (swizzled), coalesced stores.
        __syncthreads();                       // all As/Ws reads complete
        for (int mi = 0; mi < 4; ++mi)
            for (int ni = 0; ni < 4; ++ni) {
                int n_l = wn * 64 + ni * 16 + l15;
                int m_b = wm * 64 + mi * 16 + quad * 4;
                f16x4 hv = {(_Float16)acc[mi][ni][0], (_Float16)acc[mi][ni][1],
                            (_Float16)acc[mi][ni][2], (_Float16)acc[mi][ni][3]};
                *(f16x4*)(smem + n_l * 256 + ((m_b * 2) ^ ((n_l & 7) << 4))) = hv;
            }
        __syncthreads();
        int b = m0 >> 11, sb = m0 & (Ss - 1);
        for (int p = 0; p < 8; ++p) {
            int cid = p * 256 + t;             // 2048 chunks: 128 rows x 16
            int rown = cid >> 4, c16 = cid & 15;
            f16x8 v = *(const f16x8*)(smem + rown * 256 +
                                      ((c16 * 16) ^ ((rown & 7) << 4)));
            int n = n0 + rown;
            int h = n >> 6, d = n & 63;
            *(f16x8*)&Vd[(((size_t)(b * Hh + h) * Dk + d) << 11) + sb + c16 * 8] = v;
        }
    } else {
        _Float16* Y = (z == 0) ? Qd : Kd;
        float osc = (z == 0) ? QSC : 1.0f;
        for (int mi = 0; mi < 4; ++mi)
            for (int ni = 0; ni < 4; ++ni)
                for (int r = 0; r < 4; ++r) {
                    int m = m0 + wm * 64 + mi * 16 + quad * 4 + r;
                    int n = n0 + wn * 64 + ni * 16 + l15;
                    int b = m >> 11, s = m & (Ss - 1);
                    int h = n >> 6,  d = n & 63;
                    Y[(((size_t)(b * Hh + h) * Ss + s) << 6) + d] =
                        (_Float16)(acc[mi][ni][r] * osc);
                }
    }
}

// ---------------------------------------------------------------------------
// Out-projection: out = HO(f16) @ Wo^T -> f32. 128x64 tile.
// XCD-chunked tile mapping for HO panel L2 residency.
__global__ __launch_bounds__(256) void gemm_out(
    const _Float16* __restrict__ HO, const _Float16* __restrict__ Woh,
    float* __restrict__ out)
{
    __shared__ _Float16 As[128 * 32];
    __shared__ _Float16 Ws[64 * 32];
    int t = threadIdx.x, lane = t & 63, w = t >> 6;
    int quad = lane >> 4, l15 = lane & 15;
    // XCD-chunked bijection: 512 tiles, chunk 64/XCD, bx fastest in chunk.
    int orig = blockIdx.y * 16 + blockIdx.x;
    int wgid = (orig & 7) * 64 + (orig >> 3);
    int n0 = (wgid & 15) * 64, m0 = (wgid >> 4) * 128;

    f32x4 acc[2][4] = {};
    for (int k0 = 0; k0 < Dm; k0 += 32) {
        __syncthreads();
        for (int j = 0; j < 2; ++j) {
            int ca = w * 128 + j * 64 + lane;
            int row = ca >> 2, c8 = (ca & 3) * 8;
            gl_lds16(&HO[(size_t)(m0 + row) * Dm + k0 + c8],
                     &As[(size_t)(w * 128 + j * 64) * 8]);
        }
        {
            int cw = w * 64 + lane;
            int row = cw >> 2, c8 = (cw & 3) * 8;
            gl_lds16(&Woh[(size_t)(n0 + row) * Dm + k0 + c8],
                     &Ws[(size_t)(w * 64) * 8]);
        }
        __syncthreads();
        f16x8 af[2], bf[4];
        for (int mi = 0; mi < 2; ++mi)
            af[mi] = *(const f16x8*)&As[(w * 32 + mi * 16 + l15) * 32 + quad * 8];
        for (int ni = 0; ni < 4; ++ni)
            bf[ni] = *(const f16x8*)&Ws[(ni * 16 + l15) * 32 + quad * 8];
        for (int mi = 0; mi < 2; ++mi)
            for (int ni = 0; ni < 4; ++ni)
                acc[mi][ni] = __builtin_amdgcn_mfma_f32_16x16x32_f16(
                    af[mi], bf[ni], acc[mi][ni], 0, 0, 0);
    }
    for (int mi = 0; mi < 2; ++mi)
        for (int ni = 0; ni < 4; ++ni)
            for (int r = 0; r < 4; ++r) {
                int m = m0 + w * 32 + mi * 16 + quad * 4 + r;
                int n = n0 + ni * 16 + l15;
                out[(size_t)m * Dm + n] = acc[mi][ni][r];
            }
}

// ---------------------------------------------------------------------------
// Flash attention v7 (m == 0): k-split x2, 128-q tile, 32 q/wave,
// transposed-S, register-prefetch staging with XOR-swizzled LDS layouts
// for Ks, Vs, AND Ps (conflict-free b128/b64 access). [Frozen: v8/v9/v10
// variants all landed 52-58 us; this is the plateau's best schedule.]
// Writes RAW partial O (f16) and partial l per (ks, bh, q).
__global__ __launch_bounds__(256) void flash_kernel(
    const _Float16* __restrict__ Qh, const _Float16* __restrict__ Kh,
    const _Float16* __restrict__ Vt, _Float16* __restrict__ Op,
    float* __restrict__ lp)
{
    __shared__ alignas(16) char Ks[8192];      // 64 rows x 128B, swizzled
    __shared__ alignas(16) char Vs[8192];      // Vs[d][k], swizzled
    __shared__ alignas(16) char Ps[4][4096];   // per-wave P[q][k], swizzled
    int t = threadIdx.x;
    int lane = t & 63, w = t >> 6;
    int quad = lane >> 4, l15 = lane & 15;
    int bh = blockIdx.x;
    int q0 = blockIdx.y * 128 + w * 32;
    int ks = blockIdx.z;
    int kt0 = ks * 16, kt1 = kt0 + 16;

    const _Float16* Qp = Qh + (size_t)bh * Ss * Dk;
    const _Float16* Kp = Kh + (size_t)bh * Ss * Dk;
    const _Float16* Vp = Vt + (size_t)bh * Dk * Ss;

    f16x8 qf[2][2];
#pragma unroll
    for (int qh = 0; qh < 2; ++qh)
#pragma unroll
        for (int kf = 0; kf < 2; ++kf)
            qf[qh][kf] = *(const f16x8*)
                &Qp[(size_t)(q0 + qh * 16 + l15) * Dk + kf * 32 + quad * 8];

    const _Float16 one = (_Float16)1.0f;
    const f16x8 ones = {one, one, one, one, one, one, one, one};

    // staging coords: thread t covers rows (t>>3), (t>>3)+32; 16B col (t&7)*16
    int srow0 = t >> 3;
    int colh  = (t & 7) * 8;                   // halves
    int sw0 = srow0 * 128 + ((colh * 2) ^ ((srow0 & 7) << 4));
    int sw1 = sw0 + 32 * 128;                  // (srow0+32)&7 == srow0&7
    int swz = (l15 & 7) << 4;                  // read-side XOR for row l15

    // prefetch first k-tile into registers
    f16x8 kr0 = *(const f16x8*)&Kp[(size_t)(kt0 * 64 + srow0) * Dk + colh];
    f16x8 kr1 = *(const f16x8*)&Kp[(size_t)(kt0 * 64 + srow0 + 32) * Dk + colh];
    f16x8 vr0 = *(const f16x8*)&Vp[(size_t)srow0 * Ss + kt0 * 64 + colh];
    f16x8 vr1 = *(const f16x8*)&Vp[(size_t)(srow0 + 32) * Ss + kt0 * 64 + colh];

    f32x4 o_acc[2][4] = {};
    f32x4 l_acc[2] = {};
    char* Pw = Ps[w];

    for (int kt = kt0; kt < kt1; ++kt) {
        __syncthreads();                 // prev iter's LDS reads complete
        *(f16x8*)(Ks + sw0) = kr0;
        *(f16x8*)(Ks + sw1) = kr1;
        *(f16x8*)(Vs + sw0) = vr0;
        *(f16x8*)(Vs + sw1) = vr1;
        if (kt + 1 < kt1) {              // prefetch next tile (overlaps compute)
            kr0 = *(const f16x8*)&Kp[(size_t)((kt + 1) * 64 + srow0) * Dk + colh];
            kr1 = *(const f16x8*)&Kp[(size_t)((kt + 1) * 64 + srow0 + 32) * Dk + colh];
            vr0 = *(const f16x8*)&Vp[(size_t)srow0 * Ss + (kt + 1) * 64 + colh];
            vr1 = *(const f16x8*)&Vp[(size_t)(srow0 + 32) * Ss + (kt + 1) * 64 + colh];
        }
        __syncthreads();                 // tile visible

        // S^T = K Q^T : lane regs r -> k = nt*16+quad*4+r, q = l15
#pragma unroll
        for (int nt = 0; nt < 4; ++nt) {
            const char* rb = Ks + ((nt * 16 + l15) << 7);
            f16x8 kf0 = *(const f16x8*)(rb + ((quad * 16) ^ swz));
            f16x8 kf1 = *(const f16x8*)(rb + ((64 + quad * 16) ^ swz));
#pragma unroll
            for (int qh = 0; qh < 2; ++qh) {
                f32x4 z = {};
                z = __builtin_amdgcn_mfma_f32_16x16x32_f16(kf0, qf[qh][0], z, 0, 0, 0);
                z = __builtin_amdgcn_mfma_f32_16x16x32_f16(kf1, qf[qh][1], z, 0, 0, 0);
                // Q was pre-scaled by 0.125*log2e -> p = 2^z
                f16x2 h0 = pk_f16(exp2_fast(z[0]), exp2_fast(z[1]));
                f16x2 h1 = pk_f16(exp2_fast(z[2]), exp2_fast(z[3]));
                f16x4 hv = {h0[0], h0[1], h1[0], h1[1]};
                // Ps[q = qh*16+l15][k = nt*16+quad*4], swizzled by row
                int prow = qh * 16 + l15;
                *(f16x4*)(Pw + prow * 128 +
                          (((nt * 32 + quad * 8)) ^ ((prow & 7) << 4))) = hv;
            }
        }

        // PV: O[q][d] += P V ; l[q] += P * 1 (row-sum on the MFMA pipe)
        f16x8 vf[4][2];
#pragma unroll
        for (int dt = 0; dt < 4; ++dt) {
            const char* rb = Vs + ((dt * 16 + l15) << 7);
            vf[dt][0] = *(const f16x8*)(rb + ((quad * 16) ^ swz));
            vf[dt][1] = *(const f16x8*)(rb + ((64 + quad * 16) ^ swz));
        }
#pragma unroll
        for (int qh = 0; qh < 2; ++qh) {
            const char* pr = Pw + ((qh * 16 + l15) << 7);
            f16x8 pf0 = *(const f16x8*)(pr + ((quad * 16) ^ swz));
            f16x8 pf1 = *(const f16x8*)(pr + ((64 + quad * 16) ^ swz));
            l_acc[qh] = __builtin_amdgcn_mfma_f32_16x16x32_f16(
                pf0, ones, l_acc[qh], 0, 0, 0);
            l_acc[qh] = __builtin_amdgcn_mfma_f32_16x16x32_f16(
                pf1, ones, l_acc[qh], 0, 0, 0);
#pragma unroll
            for (int dt = 0; dt < 4; ++dt) {
                o_acc[qh][dt] = __builtin_amdgcn_mfma_f32_16x16x32_f16(
                    pf0, vf[dt][0], o_acc[qh][dt], 0, 0, 0);
                o_acc[qh][dt] = __builtin_amdgcn_mfma_f32_16x16x32_f16(
                    pf1, vf[dt][1], o_acc[qh][dt], 0, 0, 0);
            }
        }
    }

    // store raw partials: Op[ks][bh][q][d], lp[ks][bh*Ss + q]
    // l_acc C-layout: every l15 column holds l[q = quad*4 + r]; use l15==0.
    _Float16* Od = Op + (size_t)ks * (Bq * Hh * Ss * Dk) + (size_t)bh * Ss * Dk;
#pragma unroll
    for (int qh = 0; qh < 2; ++qh) {
#pragma unroll
        for (int dt = 0; dt < 4; ++dt)
#pragma unroll
            for (int r = 0; r < 4; ++r) {
                int q = q0 + qh * 16 + quad * 4 + r;
                Od[(size_t)q * Dk + dt * 16 + l15] = (_Float16)o_acc[qh][dt][r];
            }
        if (l15 == 0)
#pragma unroll
            for (int r = 0; r < 4; ++r)
                lp[(size_t)ks * 65536 + (size_t)bh * Ss + q0 + qh * 16 +
                   quad * 4 + r] = l_acc[qh][r];
    }
}

// ---------------------------------------------------------------------------
// Fold the 2 k-split partials: HO = (O0+O1)/l, lw = l0+l1.
__global__ __launch_bounds__(256) void reduce_kernel(
    const _Float16* __restrict__ Op, const float* __restrict__ lp,
    _Float16* __restrict__ HO, float* __restrict__ lw)
{
    int i = blockIdx.x * 256 + threadIdx.x;    // f16x4 index, 0..1048575
    int d4  = i & 15;                          // 4-elem group within d (64)
    int row = i >> 4;                          // bh*Ss + q
    f16x4 a = ((const f16x4*)Op)[i];
    f16x4 b = ((const f16x4*)Op)[i + 1048576];
    float l = lp[row] + lp[65536 + row];
    float inv = rcp_fast(l);
    int bh = row >> 11, q = row & (Ss - 1);
    int b_ = bh >> 4,  h = bh & 15;
    f16x4 o;
    for (int j = 0; j < 4; ++j)
        o[j] = (_Float16)(((float)a[j] + (float)b[j]) * inv);
    *(f16x4*)&HO[((size_t)(b_ * Ss + q)) * Dm + h * Dk + d4 * 4] = o;
    if (d4 == 0) lw[row] = l;
}

// ---------------------------------------------------------------------------
// attn_weights = mean over heads of exp2(s)/l. R5 version: reg-staged K,
// 2 barriers/head, Q/l reg-prefetch, XOR-swizzled Ks layout.
__global__ __launch_bounds__(256) void attn_mean_kernel(
    const _Float16* __restrict__ Qh, const _Float16* __restrict__ Kh,
    const float* __restrict__ lw, float* __restrict__ out_attn)
{
    __shared__ alignas(16) char Ks[8192];      // 64 rows x 128B, swizzled
    int t = threadIdx.x;
    int lane = t & 63, w = t >> 6;
    int quad = lane >> 4, l15 = lane & 15;
    int k0 = blockIdx.x * 64;
    int q0 = blockIdx.y * 128;
    int b  = blockIdx.z;
    int qrow = q0 + w * 32;

    int srow0 = t >> 3;
    int colh  = (t & 7) * 8;
    int sw0 = srow0 * 128 + ((colh * 2) ^ ((srow0 & 7) << 4));
    int sw1 = sw0 + 32 * 128;
    int swz = (l15 & 7) << 4;

    f16x8 kr0, kr1, qn[2][2];
    float4 ln[2];
    {
        size_t base = (size_t)(b * Hh) * Ss;
        kr0 = *(const f16x8*)&Kh[(base + k0 + srow0) * Dk + colh];
        kr1 = *(const f16x8*)&Kh[(base + k0 + srow0 + 32) * Dk + colh];
#pragma unroll
        for (int qh = 0; qh < 2; ++qh) {
            qn[qh][0] = *(const f16x8*)&Qh[(base + qrow + qh * 16 + l15) * Dk + quad * 8];
            qn[qh][1] = *(const f16x8*)&Qh[(base + qrow + qh * 16 + l15) * Dk + 32 + quad * 8];
            ln[qh] = *(const float4*)&lw[base + qrow + qh * 16 + quad * 4];
        }
    }

    f32x4 acc[2][4] = {};
    for (int h = 0; h < Hh; ++h) {
        __syncthreads();
        *(f16x8*)(Ks + sw0) = kr0;
        *(f16x8*)(Ks + sw1) = kr1;
        f16x8 qf[2][2];
        float4 lv[2];
#pragma unroll
        for (int qh = 0; qh < 2; ++qh) {
            qf[qh][0] = qn[qh][0]; qf[qh][1] = qn[qh][1]; lv[qh] = ln[qh];
        }
        if (h < Hh - 1) {
            size_t base = (size_t)(b * Hh + h + 1) * Ss;
            kr0 = *(const f16x8*)&Kh[(base + k0 + srow0) * Dk + colh];
            kr1 = *(const f16x8*)&Kh[(base + k0 + srow0 + 32) * Dk + colh];
#pragma unroll
            for (int qh = 0; qh < 2; ++qh) {
                qn[qh][0] = *(const f16x8*)&Qh[(base + qrow + qh * 16 + l15) * Dk + quad * 8];
                qn[qh][1] = *(const f16x8*)&Qh[(base + qrow + qh * 16 + l15) * Dk + 32 + quad * 8];
                ln[qh] = *(const float4*)&lw[base + qrow + qh * 16 + quad * 4];
            }
        }
        __syncthreads();

        float ir[2][4];
#pragma unroll
        for (int qh = 0; qh < 2; ++qh) {
            ir[qh][0] = rcp_fast(lv[qh].x); ir[qh][1] = rcp_fast(lv[qh].y);
            ir[qh][2] = rcp_fast(lv[qh].z); ir[qh][3] = rcp_fast(lv[qh].w);
        }
#pragma unroll
        for (int nt = 0; nt < 4; ++nt) {
            const char* rb = Ks + ((nt * 16 + l15) << 7);
            f16x8 b0 = *(const f16x8*)(rb + ((quad * 16) ^ swz));
            f16x8 b1 = *(const f16x8*)(rb + ((64 + quad * 16) ^ swz));
#pragma unroll
            for (int qh = 0; qh < 2; ++qh) {
                f32x4 z = {};
                z = __builtin_amdgcn_mfma_f32_16x16x32_f16(qf[qh][0], b0, z, 0, 0, 0);
                z = __builtin_amdgcn_mfma_f32_16x16x32_f16(qf[qh][1], b1, z, 0, 0, 0);
#pragma unroll
                for (int r = 0; r < 4; ++r)
                    acc[qh][nt][r] += exp2_fast(z[r]) * ir[qh][r];
            }
        }
    }

#pragma unroll
    for (int qh = 0; qh < 2; ++qh)
#pragma unroll
        for (int nt = 0; nt < 4; ++nt)
#pragma unroll
            for (int r = 0; r < 4; ++r) {
                int q = qrow + qh * 16 + quad * 4 + r;
                out_attn[((size_t)(b * Ss + q)) * Ss + k0 + nt * 16 + l15] =
                    acc[qh][nt][r] * (1.0f / Hh);
            }
}

// ---------------------------------------------------------------------------
extern "C" void kernel_launch(void* const* d_in, const int* in_sizes, int n_in,
                              void* d_out, int out_size, void* d_ws, size_t ws_size,
                              hipStream_t stream) {
    const float* query = (const float*)d_in[0];
    const float* key   = (const float*)d_in[1];
    const float* value = (const float*)d_in[2];
    const float* Wq    = (const float*)d_in[3];
    const float* Wk    = (const float*)d_in[4];
    const float* Wv    = (const float*)d_in[5];
    const float* Wo    = (const float*)d_in[6];

    float* out      = (float*)d_out;                  // (B,S,Dm) f32
    float* attn_out = out + (size_t)4194304;          // (B,S,S)  f32, 33.55 MB

    // attn region staging timeline (R5 plan):
    //   [0,     8.39M): HO f16          (reduce writes, gemm_out reads)
    //   [8.39M, 33.55M): qf|kf|vf f16   (convert->gemm_qkv), then REUSED as
    //                    Op0|Op1 f16 partials + lp f32 (flash->reduce)
    _Float16* HO  = (_Float16*)attn_out;
    _Float16* qf  = (_Float16*)(attn_out + 2097152);
    _Float16* kf  = qf + 4194304;
    _Float16* vf  = kf + 4194304;
    _Float16* Op  = qf;                               // 2 x 4194304 halves
    float*    lp  = (float*)(Op + 2 * 4194304);       // 2 x 65536 floats

    _Float16* Qh = (_Float16*)d_ws;
    _Float16* Kh = Qh + (size_t)4194304;
    _Float16* Vt = Kh + (size_t)4194304;
    _Float16* Wh = Vt + (size_t)4194304;              // Wq|Wk|Wv|Wo f16
    float*    lw = (float*)(Wh + (size_t)4194304);

    convert_kernel<<<dim3(256, 7), 256, 0, stream>>>(
        query, key, value, Wq, Wk, Wv, Wo, qf, kf, vf, Wh);

    gemm_qkv<<<dim3(8, 32, 3), 256, 0, stream>>>(qf, kf, vf, Wh, Qh, Kh, Vt);

    flash_kernel<<<dim3(Bq * Hh, Ss / 128, 2), 256, 0, stream>>>(Qh, Kh, Vt, Op, lp);

    reduce_kernel<<<4096, 256, 0, stream>>>(Op, lp, HO, lw);

    gemm_out<<<dim3(16, 32), 256, 0, stream>>>(HO, Wh + (size_t)3 * 1048576, out);

    attn_mean_kernel<<<dim3(Ss / 64, Ss / 128, Bq), 256, 0, stream>>>(
        Qh, Kh, lw, attn_out);
}

// Round 10
// 256.930 us; speedup vs baseline: 1.0980x; 1.0396x over previous
//
#include <hip/hip_runtime.h>
#include <hip/hip_bf16.h>

#define Bq 2
#define Hh 16
#define Ss 2048
#define Dm 1024
#define Dk 64
// softmax scale 1/sqrt(64)=0.125 is pre-folded (with log2e) into Q at the
// gemm_qkv epilogue: QSC = 0.125 * log2(e). flash/attn_mean then use exp2.
#define QSC 0.18033688f

typedef _Float16 f16x8 __attribute__((ext_vector_type(8)));
typedef _Float16 f16x4 __attribute__((ext_vector_type(4)));
typedef _Float16 f16x2 __attribute__((ext_vector_type(2)));
typedef float    f32x4 __attribute__((ext_vector_type(4)));

// MFMA fragment layout (16x16x32 f16):
//   A: lane holds A[m = lane&15][k = (lane>>4)*8 + j], j=0..7  (16B contiguous)
//   B: lane holds B[k = (lane>>4)*8 + j][n = lane&15]   (same register shape)
//   C/D: col = lane&15, row = (lane>>4)*4 + reg
//
// LDS tiles are stored as [row][128B] with XOR swizzle byte ^= ((row&7)<<4):
// write-side and read-side use the same involution -> bank-group-even access.

__device__ __forceinline__ void gl_lds16(const void* g, void* lds) {
    __builtin_amdgcn_global_load_lds(
        (const __attribute__((address_space(1))) void*)g,
        (__attribute__((address_space(3))) void*)lds, 16, 0, 0);
}

extern "C" __device__ float __ocml_exp2_f32(float);

__device__ __forceinline__ float exp2_fast(float x) {
#if __has_builtin(__builtin_amdgcn_exp2f)
    return __builtin_amdgcn_exp2f(x);     // v_exp_f32: D = 2^S0
#else
    return __ocml_exp2_f32(x);
#endif
}

__device__ __forceinline__ float rcp_fast(float x) {
#if __has_builtin(__builtin_amdgcn_rcpf)
    return __builtin_amdgcn_rcpf(x);      // v_rcp_f32, ~1 ulp
#else
    float r; asm("v_rcp_f32 %0, %1" : "=v"(r) : "v"(x)); return r;
#endif
}

__device__ __forceinline__ f16x2 pk_f16(float a, float b) {
    return __builtin_bit_cast(f16x2, __builtin_amdgcn_cvt_pkrtz(a, b));
}

// ---------------------------------------------------------------------------
// Convert all f32 inputs to f16 once.
__global__ __launch_bounds__(256) void convert_kernel(
    const float* __restrict__ q, const float* __restrict__ k,
    const float* __restrict__ v, const float* __restrict__ wq,
    const float* __restrict__ wk, const float* __restrict__ wv,
    const float* __restrict__ wo,
    _Float16* __restrict__ qd, _Float16* __restrict__ kd,
    _Float16* __restrict__ vd, _Float16* __restrict__ wd)
{
    int seg = blockIdx.y;
    const float* src; _Float16* dst; int n4;
    switch (seg) {
        case 0: src = q; dst = qd; n4 = 1048576; break;
        case 1: src = k; dst = kd; n4 = 1048576; break;
        case 2: src = v; dst = vd; n4 = 1048576; break;
        default:
            src = (seg == 3) ? wq : (seg == 4) ? wk : (seg == 5) ? wv : wo;
            dst = wd + (size_t)(seg - 3) * 1048576;
            n4 = 262144;
    }
    for (int i = blockIdx.x * 256 + threadIdx.x; i < n4; i += gridDim.x * 256) {
        float4 x = ((const float4*)src)[i];
        f16x4 h = {(_Float16)x.x, (_Float16)x.y, (_Float16)x.z, (_Float16)x.w};
        ((f16x4*)dst)[i] = h;
    }
}

// ---------------------------------------------------------------------------
// Fused Q/K/V projection GEMM (f16 in, global_load_lds staging, 128x128 tile).
// z==0 (Q) output is pre-scaled by QSC so attention kernels can use raw exp2.
// z==2 (V) epilogue: LDS-transpose then COALESCED 16B stores of V^T rows.
// XCD-chunked tile mapping for A/W panel L2 residency.
__global__ __launch_bounds__(256) void gemm_qkv(
    const _Float16* __restrict__ qf, const _Float16* __restrict__ kf,
    const _Float16* __restrict__ vf, const _Float16* __restrict__ Wh,
    _Float16* __restrict__ Qd, _Float16* __restrict__ Kd,
    _Float16* __restrict__ Vd)
{
    __shared__ alignas(16) char smem[32768];
    _Float16* As = (_Float16*)smem;            // 128*32 f16 (8 KB)
    _Float16* Ws = (_Float16*)(smem + 8192);   // 128*32 f16 (8 KB)
    int z = blockIdx.z;
    const _Float16* A = (z == 0) ? qf : (z == 1) ? kf : vf;
    const _Float16* W = Wh + (size_t)z * (Dm * Dm);
    int t = threadIdx.x, lane = t & 63, w = t >> 6;
    int quad = lane >> 4, l15 = lane & 15;
    int wm = w & 1, wn = w >> 1;
    // XCD-chunked bijection: 256 tiles/z, chunk 32/XCD, bx fastest in chunk.
    int orig = blockIdx.y * 8 + blockIdx.x;
    int wgid = (orig & 7) * 32 + (orig >> 3);
    int n0 = (wgid & 7) * 128, m0 = (wgid >> 3) * 128;

    f32x4 acc[4][4] = {};
    for (int k0 = 0; k0 < Dm; k0 += 32) {
        __syncthreads();
        for (int j = 0; j < 2; ++j) {
            int ca = w * 128 + j * 64 + lane;
            int row = ca >> 2, c8 = (ca & 3) * 8;
            gl_lds16(&A[(size_t)(m0 + row) * Dm + k0 + c8],
                     &As[(size_t)(w * 128 + j * 64) * 8]);
            gl_lds16(&W[(size_t)(n0 + row) * Dm + k0 + c8],
                     &Ws[(size_t)(w * 128 + j * 64) * 8]);
        }
        __syncthreads();
        f16x8 af[4], bf[4];
        for (int mi = 0; mi < 4; ++mi)
            af[mi] = *(const f16x8*)&As[(wm * 64 + mi * 16 + l15) * 32 + quad * 8];
        for (int ni = 0; ni < 4; ++ni)
            bf[ni] = *(const f16x8*)&Ws[(wn * 64 + ni * 16 + l15) * 32 + quad * 8];
        for (int mi = 0; mi < 4; ++mi)
            for (int ni = 0; ni < 4; ++ni)
                acc[mi][ni] = __builtin_amdgcn_mfma_f32_16x16x32_f16(
                    af[mi], bf[ni], acc[mi][ni], 0, 0, 0);
    }

    if (z == 2) {
        // V^T epilogue: C^T tile into LDS (swizzled), coalesced stores.
        __syncthreads();                       // all As/Ws reads complete
        for (int mi = 0; mi < 4; ++mi)
            for (int ni = 0; ni < 4; ++ni) {
                int n_l = wn * 64 + ni * 16 + l15;
                int m_b = wm * 64 + mi * 16 + quad * 4;
                f16x4 hv = {(_Float16)acc[mi][ni][0], (_Float16)acc[mi][ni][1],
                            (_Float16)acc[mi][ni][2], (_Float16)acc[mi][ni][3]};
                *(f16x4*)(smem + n_l * 256 + ((m_b * 2) ^ ((n_l & 7) << 4))) = hv;
            }
        __syncthreads();
        int b = m0 >> 11, sb = m0 & (Ss - 1);
        for (int p = 0; p < 8; ++p) {
            int cid = p * 256 + t;             // 2048 chunks: 128 rows x 16
            int rown = cid >> 4, c16 = cid & 15;
            f16x8 v = *(const f16x8*)(smem + rown * 256 +
                                      ((c16 * 16) ^ ((rown & 7) << 4)));
            int n = n0 + rown;
            int h = n >> 6, d = n & 63;
            *(f16x8*)&Vd[(((size_t)(b * Hh + h) * Dk + d) << 11) + sb + c16 * 8] = v;
        }
    } else {
        _Float16* Y = (z == 0) ? Qd : Kd;
        float osc = (z == 0) ? QSC : 1.0f;
        for (int mi = 0; mi < 4; ++mi)
            for (int ni = 0; ni < 4; ++ni)
                for (int r = 0; r < 4; ++r) {
                    int m = m0 + wm * 64 + mi * 16 + quad * 4 + r;
                    int n = n0 + wn * 64 + ni * 16 + l15;
                    int b = m >> 11, s = m & (Ss - 1);
                    int h = n >> 6,  d = n & 63;
                    Y[(((size_t)(b * Hh + h) * Ss + s) << 6) + d] =
                        (_Float16)(acc[mi][ni][r] * osc);
                }
    }
}

// ---------------------------------------------------------------------------
// Flash attention v7 (m == 0): k-split x2, 128-q tile, 32 q/wave,
// transposed-S, register-prefetch staging with XOR-swizzled LDS layouts
// for Ks, Vs, AND Ps (conflict-free b128/b64 access). [Frozen.]
// Writes RAW partial O (f16) and partial l per (ks, bh, q).
__global__ __launch_bounds__(256) void flash_kernel(
    const _Float16* __restrict__ Qh, const _Float16* __restrict__ Kh,
    const _Float16* __restrict__ Vt, _Float16* __restrict__ Op,
    float* __restrict__ lp)
{
    __shared__ alignas(16) char Ks[8192];      // 64 rows x 128B, swizzled
    __shared__ alignas(16) char Vs[8192];      // Vs[d][k], swizzled
    __shared__ alignas(16) char Ps[4][4096];   // per-wave P[q][k], swizzled
    int t = threadIdx.x;
    int lane = t & 63, w = t >> 6;
    int quad = lane >> 4, l15 = lane & 15;
    int bh = blockIdx.x;
    int q0 = blockIdx.y * 128 + w * 32;
    int ks = blockIdx.z;
    int kt0 = ks * 16, kt1 = kt0 + 16;

    const _Float16* Qp = Qh + (size_t)bh * Ss * Dk;
    const _Float16* Kp = Kh + (size_t)bh * Ss * Dk;
    const _Float16* Vp = Vt + (size_t)bh * Dk * Ss;

    f16x8 qf[2][2];
#pragma unroll
    for (int qh = 0; qh < 2; ++qh)
#pragma unroll
        for (int kf = 0; kf < 2; ++kf)
            qf[qh][kf] = *(const f16x8*)
                &Qp[(size_t)(q0 + qh * 16 + l15) * Dk + kf * 32 + quad * 8];

    const _Float16 one = (_Float16)1.0f;
    const f16x8 ones = {one, one, one, one, one, one, one, one};

    // staging coords: thread t covers rows (t>>3), (t>>3)+32; 16B col (t&7)*16
    int srow0 = t >> 3;
    int colh  = (t & 7) * 8;                   // halves
    int sw0 = srow0 * 128 + ((colh * 2) ^ ((srow0 & 7) << 4));
    int sw1 = sw0 + 32 * 128;                  // (srow0+32)&7 == srow0&7
    int swz = (l15 & 7) << 4;                  // read-side XOR for row l15

    // prefetch first k-tile into registers
    f16x8 kr0 = *(const f16x8*)&Kp[(size_t)(kt0 * 64 + srow0) * Dk + colh];
    f16x8 kr1 = *(const f16x8*)&Kp[(size_t)(kt0 * 64 + srow0 + 32) * Dk + colh];
    f16x8 vr0 = *(const f16x8*)&Vp[(size_t)srow0 * Ss + kt0 * 64 + colh];
    f16x8 vr1 = *(const f16x8*)&Vp[(size_t)(srow0 + 32) * Ss + kt0 * 64 + colh];

    f32x4 o_acc[2][4] = {};
    f32x4 l_acc[2] = {};
    char* Pw = Ps[w];

    for (int kt = kt0; kt < kt1; ++kt) {
        __syncthreads();                 // prev iter's LDS reads complete
        *(f16x8*)(Ks + sw0) = kr0;
        *(f16x8*)(Ks + sw1) = kr1;
        *(f16x8*)(Vs + sw0) = vr0;
        *(f16x8*)(Vs + sw1) = vr1;
        if (kt + 1 < kt1) {              // prefetch next tile (overlaps compute)
            kr0 = *(const f16x8*)&Kp[(size_t)((kt + 1) * 64 + srow0) * Dk + colh];
            kr1 = *(const f16x8*)&Kp[(size_t)((kt + 1) * 64 + srow0 + 32) * Dk + colh];
            vr0 = *(const f16x8*)&Vp[(size_t)srow0 * Ss + (kt + 1) * 64 + colh];
            vr1 = *(const f16x8*)&Vp[(size_t)(srow0 + 32) * Ss + (kt + 1) * 64 + colh];
        }
        __syncthreads();                 // tile visible

        // S^T = K Q^T : lane regs r -> k = nt*16+quad*4+r, q = l15
#pragma unroll
        for (int nt = 0; nt < 4; ++nt) {
            const char* rb = Ks + ((nt * 16 + l15) << 7);
            f16x8 kf0 = *(const f16x8*)(rb + ((quad * 16) ^ swz));
            f16x8 kf1 = *(const f16x8*)(rb + ((64 + quad * 16) ^ swz));
#pragma unroll
            for (int qh = 0; qh < 2; ++qh) {
                f32x4 z = {};
                z = __builtin_amdgcn_mfma_f32_16x16x32_f16(kf0, qf[qh][0], z, 0, 0, 0);
                z = __builtin_amdgcn_mfma_f32_16x16x32_f16(kf1, qf[qh][1], z, 0, 0, 0);
                // Q was pre-scaled by 0.125*log2e -> p = 2^z
                f16x2 h0 = pk_f16(exp2_fast(z[0]), exp2_fast(z[1]));
                f16x2 h1 = pk_f16(exp2_fast(z[2]), exp2_fast(z[3]));
                f16x4 hv = {h0[0], h0[1], h1[0], h1[1]};
                // Ps[q = qh*16+l15][k = nt*16+quad*4], swizzled by row
                int prow = qh * 16 + l15;
                *(f16x4*)(Pw + prow * 128 +
                          (((nt * 32 + quad * 8)) ^ ((prow & 7) << 4))) = hv;
            }
        }

        // PV: O[q][d] += P V ; l[q] += P * 1 (row-sum on the MFMA pipe)
        f16x8 vf[4][2];
#pragma unroll
        for (int dt = 0; dt < 4; ++dt) {
            const char* rb = Vs + ((dt * 16 + l15) << 7);
            vf[dt][0] = *(const f16x8*)(rb + ((quad * 16) ^ swz));
            vf[dt][1] = *(const f16x8*)(rb + ((64 + quad * 16) ^ swz));
        }
#pragma unroll
        for (int qh = 0; qh < 2; ++qh) {
            const char* pr = Pw + ((qh * 16 + l15) << 7);
            f16x8 pf0 = *(const f16x8*)(pr + ((quad * 16) ^ swz));
            f16x8 pf1 = *(const f16x8*)(pr + ((64 + quad * 16) ^ swz));
            l_acc[qh] = __builtin_amdgcn_mfma_f32_16x16x32_f16(
                pf0, ones, l_acc[qh], 0, 0, 0);
            l_acc[qh] = __builtin_amdgcn_mfma_f32_16x16x32_f16(
                pf1, ones, l_acc[qh], 0, 0, 0);
#pragma unroll
            for (int dt = 0; dt < 4; ++dt) {
                o_acc[qh][dt] = __builtin_amdgcn_mfma_f32_16x16x32_f16(
                    pf0, vf[dt][0], o_acc[qh][dt], 0, 0, 0);
                o_acc[qh][dt] = __builtin_amdgcn_mfma_f32_16x16x32_f16(
                    pf1, vf[dt][1], o_acc[qh][dt], 0, 0, 0);
            }
        }
    }

    // store raw partials: Op[ks][bh][q][d], lp[ks][bh*Ss + q]
    // l_acc C-layout: every l15 column holds l[q = quad*4 + r]; use l15==0.
    _Float16* Od = Op + (size_t)ks * (Bq * Hh * Ss * Dk) + (size_t)bh * Ss * Dk;
#pragma unroll
    for (int qh = 0; qh < 2; ++qh) {
#pragma unroll
        for (int dt = 0; dt < 4; ++dt)
#pragma unroll
            for (int r = 0; r < 4; ++r) {
                int q = q0 + qh * 16 + quad * 4 + r;
                Od[(size_t)q * Dk + dt * 16 + l15] = (_Float16)o_acc[qh][dt][r];
            }
        if (l15 == 0)
#pragma unroll
            for (int r = 0; r < 4; ++r)
                lp[(size_t)ks * 65536 + (size_t)bh * Ss + q0 + qh * 16 +
                   quad * 4 + r] = l_acc[qh][r];
    }
}

// ---------------------------------------------------------------------------
// Fold the 2 k-split partials: HO = (O0+O1)/l, lw = l0+l1.
__global__ __launch_bounds__(256) void reduce_kernel(
    const _Float16* __restrict__ Op, const float* __restrict__ lp,
    _Float16* __restrict__ HO, float* __restrict__ lw)
{
    int i = blockIdx.x * 256 + threadIdx.x;    // f16x4 index, 0..1048575
    int d4  = i & 15;                          // 4-elem group within d (64)
    int row = i >> 4;                          // bh*Ss + q
    f16x4 a = ((const f16x4*)Op)[i];
    f16x4 b = ((const f16x4*)Op)[i + 1048576];
    float l = lp[row] + lp[65536 + row];
    float inv = rcp_fast(l);
    int bh = row >> 11, q = row & (Ss - 1);
    int b_ = bh >> 4,  h = bh & 15;
    f16x4 o;
    for (int j = 0; j < 4; ++j)
        o[j] = (_Float16)(((float)a[j] + (float)b[j]) * inv);
    *(f16x4*)&HO[((size_t)(b_ * Ss + q)) * Dm + h * Dk + d4 * 4] = o;
    if (d4 == 0) lw[row] = l;
}

// ---------------------------------------------------------------------------
// Fused tail: gemm_out (512 tiles) and attn_mean (1024 tiles) in ONE launch,
// interleaved id%3 so both kinds populate every CU from the start. The two
// are independent (gemm_out: HO x Wo; attn_mean: Q,K,lw) and individually
// latency-bound -> co-residency hides each other's stalls.
// HO lives in d_ws (Vt slot) so attn_mean's attn_out writes can't race it.
__global__ __launch_bounds__(256) void tail_kernel(
    const _Float16* __restrict__ HO, const _Float16* __restrict__ Woh,
    float* __restrict__ out, const _Float16* __restrict__ Qh,
    const _Float16* __restrict__ Kh, const float* __restrict__ lw,
    float* __restrict__ out_attn)
{
    __shared__ alignas(16) char smem[12288];
    int id = blockIdx.x;
    int t = threadIdx.x, lane = t & 63, w = t >> 6;
    int quad = lane >> 4, l15 = lane & 15;

    if (id % 3 == 0) {
        // ================= gemm_out tile: out = HO @ Wo^T =================
        int go = id / 3;                       // 0..511
        _Float16* As = (_Float16*)smem;        // 128*32 f16 (8 KB)
        _Float16* Ws = (_Float16*)(smem + 8192); // 64*32 f16 (4 KB)
        int n0 = (go & 15) * 64, m0 = (go >> 4) * 128;

        f32x4 acc[2][4] = {};
        for (int k0 = 0; k0 < Dm; k0 += 32) {
            __syncthreads();
            for (int j = 0; j < 2; ++j) {
                int ca = w * 128 + j * 64 + lane;
                int row = ca >> 2, c8 = (ca & 3) * 8;
                gl_lds16(&HO[(size_t)(m0 + row) * Dm + k0 + c8],
                         &As[(size_t)(w * 128 + j * 64) * 8]);
            }
            {
                int cw = w * 64 + lane;
                int row = cw >> 2, c8 = (cw & 3) * 8;
                gl_lds16(&Woh[(size_t)(n0 + row) * Dm + k0 + c8],
                         &Ws[(size_t)(w * 64) * 8]);
            }
            __syncthreads();
            f16x8 af[2], bf[4];
            for (int mi = 0; mi < 2; ++mi)
                af[mi] = *(const f16x8*)&As[(w * 32 + mi * 16 + l15) * 32 + quad * 8];
            for (int ni = 0; ni < 4; ++ni)
                bf[ni] = *(const f16x8*)&Ws[(ni * 16 + l15) * 32 + quad * 8];
            for (int mi = 0; mi < 2; ++mi)
                for (int ni = 0; ni < 4; ++ni)
                    acc[mi][ni] = __builtin_amdgcn_mfma_f32_16x16x32_f16(
                        af[mi], bf[ni], acc[mi][ni], 0, 0, 0);
        }
        for (int mi = 0; mi < 2; ++mi)
            for (int ni = 0; ni < 4; ++ni)
                for (int r = 0; r < 4; ++r) {
                    int m = m0 + w * 32 + mi * 16 + quad * 4 + r;
                    int n = n0 + ni * 16 + l15;
                    out[(size_t)m * Dm + n] = acc[mi][ni][r];
                }
    } else {
        // ====== attn_mean tile: mean over heads of exp2(s)/l ======
        int am = id - id / 3 - 1;              // 0..1023
        char* Ks = smem;                       // 64 rows x 128B, swizzled
        int k0 = (am & 31) * 64;
        int q0 = ((am >> 5) & 15) * 128;
        int b  = am >> 9;
        int qrow = q0 + w * 32;

        int srow0 = t >> 3;
        int colh  = (t & 7) * 8;
        int sw0 = srow0 * 128 + ((colh * 2) ^ ((srow0 & 7) << 4));
        int sw1 = sw0 + 32 * 128;
        int swz = (l15 & 7) << 4;

        f16x8 kr0, kr1, qn[2][2];
        float4 ln[2];
        {
            size_t base = (size_t)(b * Hh) * Ss;
            kr0 = *(const f16x8*)&Kh[(base + k0 + srow0) * Dk + colh];
            kr1 = *(const f16x8*)&Kh[(base + k0 + srow0 + 32) * Dk + colh];
#pragma unroll
            for (int qh = 0; qh < 2; ++qh) {
                qn[qh][0] = *(const f16x8*)&Qh[(base + qrow + qh * 16 + l15) * Dk + quad * 8];
                qn[qh][1] = *(const f16x8*)&Qh[(base + qrow + qh * 16 + l15) * Dk + 32 + quad * 8];
                ln[qh] = *(const float4*)&lw[base + qrow + qh * 16 + quad * 4];
            }
        }

        f32x4 acc[2][4] = {};
        for (int h = 0; h < Hh; ++h) {
            __syncthreads();
            *(f16x8*)(Ks + sw0) = kr0;
            *(f16x8*)(Ks + sw1) = kr1;
            f16x8 qf[2][2];
            float4 lv[2];
#pragma unroll
            for (int qh = 0; qh < 2; ++qh) {
                qf[qh][0] = qn[qh][0]; qf[qh][1] = qn[qh][1]; lv[qh] = ln[qh];
            }
            if (h < Hh - 1) {
                size_t base = (size_t)(b * Hh + h + 1) * Ss;
                kr0 = *(const f16x8*)&Kh[(base + k0 + srow0) * Dk + colh];
                kr1 = *(const f16x8*)&Kh[(base + k0 + srow0 + 32) * Dk + colh];
#pragma unroll
                for (int qh = 0; qh < 2; ++qh) {
                    qn[qh][0] = *(const f16x8*)&Qh[(base + qrow + qh * 16 + l15) * Dk + quad * 8];
                    qn[qh][1] = *(const f16x8*)&Qh[(base + qrow + qh * 16 + l15) * Dk + 32 + quad * 8];
                    ln[qh] = *(const float4*)&lw[base + qrow + qh * 16 + quad * 4];
                }
            }
            __syncthreads();

            float ir[2][4];
#pragma unroll
            for (int qh = 0; qh < 2; ++qh) {
                ir[qh][0] = rcp_fast(lv[qh].x); ir[qh][1] = rcp_fast(lv[qh].y);
                ir[qh][2] = rcp_fast(lv[qh].z); ir[qh][3] = rcp_fast(lv[qh].w);
            }
#pragma unroll
            for (int nt = 0; nt < 4; ++nt) {
                const char* rb = Ks + ((nt * 16 + l15) << 7);
                f16x8 b0 = *(const f16x8*)(rb + ((quad * 16) ^ swz));
                f16x8 b1 = *(const f16x8*)(rb + ((64 + quad * 16) ^ swz));
#pragma unroll
                for (int qh = 0; qh < 2; ++qh) {
                    f32x4 z = {};
                    z = __builtin_amdgcn_mfma_f32_16x16x32_f16(qf[qh][0], b0, z, 0, 0, 0);
                    z = __builtin_amdgcn_mfma_f32_16x16x32_f16(qf[qh][1], b1, z, 0, 0, 0);
#pragma unroll
                    for (int r = 0; r < 4; ++r)
                        acc[qh][nt][r] += exp2_fast(z[r]) * ir[qh][r];
                }
            }
        }

#pragma unroll
        for (int qh = 0; qh < 2; ++qh)
#pragma unroll
            for (int nt = 0; nt < 4; ++nt)
#pragma unroll
                for (int r = 0; r < 4; ++r) {
                    int q = qrow + qh * 16 + quad * 4 + r;
                    out_attn[((size_t)(b * Ss + q)) * Ss + k0 + nt * 16 + l15] =
                        acc[qh][nt][r] * (1.0f / Hh);
                }
    }
}

// ---------------------------------------------------------------------------
extern "C" void kernel_launch(void* const* d_in, const int* in_sizes, int n_in,
                              void* d_out, int out_size, void* d_ws, size_t ws_size,
                              hipStream_t stream) {
    const float* query = (const float*)d_in[0];
    const float* key   = (const float*)d_in[1];
    const float* value = (const float*)d_in[2];
    const float* Wq    = (const float*)d_in[3];
    const float* Wk    = (const float*)d_in[4];
    const float* Wv    = (const float*)d_in[5];
    const float* Wo    = (const float*)d_in[6];

    float* out      = (float*)d_out;                  // (B,S,Dm) f32
    float* attn_out = out + (size_t)4194304;          // (B,S,S)  f32, 33.55 MB

    // Lifetime plan (order: convert -> gemm_qkv -> flash -> reduce -> tail):
    //   attn region: qf|kf|vf f16 (convert->gemm_qkv), then REUSED as
    //                Op0|Op1 f16 partials + lp f32 (flash->reduce), then
    //                fully overwritten by tail's attn_mean output.
    //   d_ws Vt    : V^T (gemm_qkv->flash), then REUSED as HO f16
    //                (reduce->tail gemm_out). attn_mean part never reads it.
    _Float16* qf  = (_Float16*)(attn_out + 2097152);
    _Float16* kf  = qf + 4194304;
    _Float16* vf  = kf + 4194304;
    _Float16* Op  = qf;                               // 2 x 4194304 halves
    float*    lp  = (float*)(Op + 2 * 4194304);       // 2 x 65536 floats

    _Float16* Qh = (_Float16*)d_ws;
    _Float16* Kh = Qh + (size_t)4194304;
    _Float16* Vt = Kh + (size_t)4194304;
    _Float16* Wh = Vt + (size_t)4194304;              // Wq|Wk|Wv|Wo f16
    float*    lw = (float*)(Wh + (size_t)4194304);
    _Float16* HO = Vt;                                // reuse after flash

    convert_kernel<<<dim3(256, 7), 256, 0, stream>>>(
        query, key, value, Wq, Wk, Wv, Wo, qf, kf, vf, Wh);

    gemm_qkv<<<dim3(8, 32, 3), 256, 0, stream>>>(qf, kf, vf, Wh, Qh, Kh, Vt);

    flash_kernel<<<dim3(Bq * Hh, Ss / 128, 2), 256, 0, stream>>>(Qh, Kh, Vt, Op, lp);

    reduce_kernel<<<4096, 256, 0, stream>>>(Op, lp, HO, lw);

    tail_kernel<<<1536, 256, 0, stream>>>(
        HO, Wh + (size_t)3 * 1048576, out, Qh, Kh, lw, attn_out);
}